// Round 1
// baseline (230.534 us; speedup 1.0000x reference)
//
#include <hip/hip_runtime.h>

#define FIN 64
#define FOUT 64
#define KK 4

// ---------------------------------------------------------------------------
// Detect whether edge_idx was materialized as int64 (little-endian) or int32.
// If int64 with values < 2^31, every odd int32 word (high half) is zero.
// Probability of false positive with random int32 indices in [0,50000): ~0.
__global__ void detect_idx_kernel(const int* __restrict__ eidx, int* __restrict__ flag) {
    int nz = 0;
    for (int j = 1; j < 16; j += 2) nz |= eidx[j];
    *flag = (nz == 0) ? 1 : 0;
}

// ---------------------------------------------------------------------------
// out[n*64+o] = bias[o]
__global__ __launch_bounds__(256) void init_out_kernel(const float* __restrict__ bias,
                                                       float* __restrict__ out, int total) {
    int i = blockIdx.x * blockDim.x + threadIdx.x;
    if (i < total) out[i] = bias[i & 63];
}

// ---------------------------------------------------------------------------
// support[n][o][k] = sum_i x[n][i] * weight[i][o][k]
// Block = 256 threads = 4 waves; each wave computes 8 rows; lane = o.
// weight is 64 KB -> L2 resident; float4 loads reused across 8 rows in regs.
__global__ __launch_bounds__(256) void support_kernel(const float* __restrict__ x,
                                                      const float* __restrict__ weight,
                                                      float* __restrict__ sup, int n) {
    __shared__ float xs[32][64];
    const int t = threadIdx.x;
    const int rowbase = blockIdx.x * 32;

    // Stage 32 rows of x into LDS (coalesced).
    #pragma unroll
    for (int j = 0; j < 8; ++j) {
        int idx = t + j * 256;
        int r = idx >> 6, c = idx & 63;
        int gr = rowbase + r;
        xs[r][c] = (gr < n) ? x[gr * 64 + c] : 0.f;
    }
    __syncthreads();

    const int w = t >> 6;     // wave id: rows rowbase + w*8 .. +7
    const int o = t & 63;     // output feature

    float4 acc[8];
    #pragma unroll
    for (int r = 0; r < 8; ++r) acc[r] = make_float4(0.f, 0.f, 0.f, 0.f);

    #pragma unroll 4
    for (int i = 0; i < 64; ++i) {
        float4 wv = *(const float4*)&weight[i * 256 + o * 4];
        #pragma unroll
        for (int r = 0; r < 8; ++r) {
            float xv = xs[w * 8 + r][i];   // LDS broadcast
            acc[r].x += xv * wv.x;
            acc[r].y += xv * wv.y;
            acc[r].z += xv * wv.z;
            acc[r].w += xv * wv.w;
        }
    }

    #pragma unroll
    for (int r = 0; r < 8; ++r) {
        int gr = rowbase + w * 8 + r;
        if (gr < n) *(float4*)&sup[gr * 256 + o * 4] = acc[r];
    }
}

// ---------------------------------------------------------------------------
// Per edge e (one wave per edge, lane = o):
//   value[k] = exp(sig[k] * -0.5 * sum_m (diff_m - mu[m][k])^2)
//   atomicAdd(out[row*64+o], sum_k value[k] * sup[col*256 + o*4 + k])
__global__ __launch_bounds__(256) void edge_kernel(const int* __restrict__ eidx,
                                                   const float* __restrict__ spec,
                                                   const float* __restrict__ mu,   // [3][4]
                                                   const float* __restrict__ sig,  // [4]
                                                   const float* __restrict__ sup,
                                                   const int* __restrict__ flag,
                                                   float* __restrict__ out, int e_total) {
    const int tid  = blockIdx.x * blockDim.x + threadIdx.x;
    const int lane = tid & 63;
    const int wid  = tid >> 6;
    const int nw   = (gridDim.x * blockDim.x) >> 6;
    const int is64 = *flag;

    float m0[4], m1[4], m2[4], sg[4];
    #pragma unroll
    for (int k = 0; k < 4; ++k) {
        m0[k] = mu[0 * 4 + k];
        m1[k] = mu[1 * 4 + k];
        m2[k] = mu[2 * 4 + k];
        sg[k] = sig[k];
    }

    for (int e = wid; e < e_total; e += nw) {
        int row, col;
        if (is64) {
            row = eidx[2 * e];
            col = eidx[2 * (e_total + e)];
        } else {
            row = eidx[e];
            col = eidx[e_total + e];
        }

        float d0 = spec[row * 3 + 0] - spec[col * 3 + 0];
        float d1 = spec[row * 3 + 1] - spec[col * 3 + 1];
        float d2 = spec[row * 3 + 2] - spec[col * 3 + 2];

        float v[4];
        #pragma unroll
        for (int k = 0; k < 4; ++k) {
            float a = d0 - m0[k];
            float b = d1 - m1[k];
            float c = d2 - m2[k];
            float q = -0.5f * (a * a + b * b + c * c);
            v[k] = __expf(sg[k] * q);
        }

        float4 s = *(const float4*)&sup[col * 256 + lane * 4];
        float msg = s.x * v[0] + s.y * v[1] + s.z * v[2] + s.w * v[3];
        atomicAdd(&out[row * 64 + lane], msg);
    }
}

// ---------------------------------------------------------------------------
extern "C" void kernel_launch(void* const* d_in, const int* in_sizes, int n_in,
                              void* d_out, int out_size, void* d_ws, size_t ws_size,
                              hipStream_t stream) {
    const float* x      = (const float*)d_in[0];
    const int*   eidx   = (const int*)d_in[1];
    const float* spec   = (const float*)d_in[2];
    const float* weight = (const float*)d_in[3];
    const float* bias   = (const float*)d_in[4];
    const float* mu     = (const float*)d_in[5];
    const float* sig    = (const float*)d_in[6];
    float* out = (float*)d_out;

    const int N = in_sizes[0] / FIN;        // 50000
    const int E = in_sizes[1] / 2;          // 800000

    int*   flag = (int*)d_ws;                          // 4 B
    float* sup  = (float*)((char*)d_ws + 256);         // N*256 floats = 51.2 MB

    detect_idx_kernel<<<1, 1, 0, stream>>>(eidx, flag);

    init_out_kernel<<<(N * FOUT + 255) / 256, 256, 0, stream>>>(bias, out, N * FOUT);

    support_kernel<<<(N + 31) / 32, 256, 0, stream>>>(x, weight, sup, N);

    // 2048 blocks * 4 waves = 8192 waves = full-device occupancy, grid-stride.
    edge_kernel<<<2048, 256, 0, stream>>>(eidx, spec, mu, sig, sup, flag, out, E);
}